// Round 3
// baseline (311.079 us; speedup 1.0000x reference)
//
#include <hip/hip_runtime.h>
#include <cstdint>
#include <cstddef>

#define NTOK 4096           // B*S
#define DIM  1024           // D
#define HDIM 2048           // H
#define NE   8              // experts
#define BM   128            // GEMM row tile
#define MAXROWS (2*NTOK + NE*BM)   // 9216 worst-case padded slots
#define MBLK (MAXROWS/BM)          // 72 m-blocks (fixed grid)

typedef __attribute__((ext_vector_type(8))) short short8;
typedef __attribute__((ext_vector_type(4))) float f32x4;
typedef __attribute__((ext_vector_type(4))) unsigned short u16x4;

__device__ __forceinline__ unsigned short f2bf(float f) {
    union { float f; unsigned int u; } v; v.f = f;
    return (unsigned short)((v.u + 0x7FFFu + ((v.u >> 16) & 1u)) >> 16);
}

__device__ __forceinline__ void load_lds16(const void* g, void* l) {
    __builtin_amdgcn_global_load_lds(
        (const __attribute__((address_space(1))) void*)(uintptr_t)g,
        (__attribute__((address_space(3))) void*)(uintptr_t)l, 16, 0, 0);
}

// hdr layout (ints): [0..7] counts, [16..24] padded offsets (off[8]=padded_total),
//                    [32 + 16*e] cursors (one per 64B cacheline)
__global__ void init_kernel(int* hdr) {
    hdr[threadIdx.x] = 0;   // 256 ints
}

// gw [1024][8] f32 -> gwt [8][1024] f32 (so gate loads are coalesced float4)
__global__ __launch_bounds__(256) void gwt_kernel(const float* __restrict__ gw, float* __restrict__ gwt) {
    const int i = blockIdx.x * 256 + threadIdx.x;   // 8192 total
    const int d = i >> 3, e = i & 7;
    gwt[e * DIM + d] = gw[i];
}

__global__ __launch_bounds__(256) void gate_kernel(
    const float* __restrict__ x, const float* __restrict__ gwt, const float* __restrict__ gb,
    float* __restrict__ scores, int* __restrict__ eidx, int* __restrict__ hdr, float* __restrict__ aux)
{
    const int tid = threadIdx.x, lane = tid & 63, wv = tid >> 6;
    const int n = blockIdx.x * 4 + wv;
    float a[NE] = {0.f,0.f,0.f,0.f,0.f,0.f,0.f,0.f};
    const float* xr = x + (size_t)n * DIM;
    #pragma unroll
    for (int c = 0; c < 4; ++c) {
        const int d0 = c * 256 + lane * 4;
        const float4 xv = *reinterpret_cast<const float4*>(xr + d0);
        #pragma unroll
        for (int e = 0; e < NE; ++e) {
            const float4 gv = *reinterpret_cast<const float4*>(gwt + e * DIM + d0);  // coalesced
            a[e] = fmaf(xv.x, gv.x, a[e]);
            a[e] = fmaf(xv.y, gv.y, a[e]);
            a[e] = fmaf(xv.z, gv.z, a[e]);
            a[e] = fmaf(xv.w, gv.w, a[e]);
        }
    }
    #pragma unroll
    for (int e = 0; e < NE; ++e)
        #pragma unroll
        for (int off = 32; off > 0; off >>= 1)
            a[e] += __shfl_xor(a[e], off);
    if (lane == 0) {
        float lg[NE], slg = 0.f, mx = -1e30f;
        #pragma unroll
        for (int e = 0; e < NE; ++e) { lg[e] = a[e] + gb[e]; slg += lg[e]; mx = fmaxf(mx, lg[e]); }
        float se = 0.f;
        #pragma unroll
        for (int e = 0; e < NE; ++e) se += expf(lg[e] - mx);
        const float lz = mx + logf(se);
        int i0 = 0;
        #pragma unroll
        for (int e = 1; e < NE; ++e) if (lg[e] > lg[i0]) i0 = e;
        int i1 = (i0 == 0) ? 1 : 0;
        #pragma unroll
        for (int e = 0; e < NE; ++e) if (e != i0 && lg[e] > lg[i1]) i1 = e;
        const float ex = expf(lg[i1] - lg[i0]);
        const float p0 = 1.f / (1.f + ex);
        scores[2*n]   = p0;
        scores[2*n+1] = ex * p0;
        eidx[2*n]   = i0;
        eidx[2*n+1] = i1;
        atomicAdd(&hdr[i0], 1);               // non-returning: pipelined
        atomicAdd(&hdr[i1], 1);
        atomicAdd(aux, slg - 8.f * lz);       // sum_e logp_e for this token
    }
}

__global__ void offsets_kernel(int* hdr) {
    if (threadIdx.x == 0) {
        int off = 0;
        for (int e = 0; e < NE; ++e) {
            hdr[16 + e] = off;
            off += (hdr[e] + BM - 1) & ~(BM - 1);
        }
        hdr[16 + NE] = off;   // padded_total
    }
}

// Block-aggregated slot assignment: 256 pairs/block, 8 returning atomics/block.
__global__ __launch_bounds__(256) void assign_kernel(
    const int* __restrict__ eidx, int* __restrict__ hdr, int* __restrict__ slot_of)
{
    __shared__ int cnt[NE];
    __shared__ int base[NE];
    const int tid = threadIdx.x;
    const int p = blockIdx.x * 256 + tid;
    if (tid < NE) cnt[tid] = 0;
    __syncthreads();
    const int e = eidx[p];
    const int pos = atomicAdd(&cnt[e], 1);          // LDS atomic: fast
    __syncthreads();
    if (tid < NE) base[tid] = atomicAdd(&hdr[32 + 16 * tid], cnt[tid]);  // own cacheline
    __syncthreads();
    slot_of[p] = hdr[16 + e] + base[e] + pos;
}

// Atomic-free gather/cast: one wave per pair.
__global__ __launch_bounds__(256) void gather_kernel(
    const float* __restrict__ x, const int* __restrict__ slot_of, unsigned short* __restrict__ xg)
{
    const int tid = threadIdx.x, lane = tid & 63, wv = tid >> 6;
    const int pair = blockIdx.x * 4 + wv;        // pair = n*2 + k
    const int n = pair >> 1;
    const int slot = slot_of[pair];
    const float* xr = x + (size_t)n * DIM;
    unsigned short* dst = xg + (size_t)slot * DIM;
    for (int d0 = lane * 4; d0 < DIM; d0 += 256) {
        const float4 xv = *reinterpret_cast<const float4*>(xr + d0);
        u16x4 o = { f2bf(xv.x), f2bf(xv.y), f2bf(xv.z), f2bf(xv.w) };
        *reinterpret_cast<u16x4*>(dst + d0) = o;
    }
}

// in: [E][R][C] f32  ->  out: [E][C][R] bf16   (gives weights in [N][K] for contiguous-K frags)
__global__ __launch_bounds__(256) void transpose_kernel(
    const float* __restrict__ in, unsigned short* __restrict__ out, int R, int C)
{
    __shared__ float tile[32][33];
    const int e = blockIdx.z;
    in  += (size_t)e * R * C;
    out += (size_t)e * R * C;
    const int c0 = blockIdx.x * 32, r0 = blockIdx.y * 32;
    const int tx = threadIdx.x, ty = threadIdx.y;
    #pragma unroll
    for (int j = 0; j < 4; ++j)
        tile[ty + 8*j][tx] = in[(size_t)(r0 + ty + 8*j) * C + c0 + tx];
    __syncthreads();
    #pragma unroll
    for (int j = 0; j < 4; ++j)
        out[(size_t)(c0 + ty + 8*j) * R + r0 + tx] = f2bf(tile[tx][ty + 8*j]);
}

// C[row][n] = (GELU? gelu : id)(A[row][:] @ B_e[:][n]);  A:[rows][KD] bf16, Bt:[E][ND][KD] bf16
template<int KD, int ND, bool GELU>
__global__ __launch_bounds__(256, 2) void gemm_kernel(
    const unsigned short* __restrict__ A, const unsigned short* __restrict__ Bt,
    void* __restrict__ Cout, const int* __restrict__ hdr)
{
    const int tid = threadIdx.x, lane = tid & 63, wv = tid >> 6;
    const int wr = wv >> 1, wc = wv & 1;
    const int row0 = blockIdx.y * BM;
    if (row0 >= hdr[16 + NE]) return;          // beyond padded_total
    int e = 0;
    while (e < NE - 1 && hdr[16 + e + 1] <= row0) ++e;
    const unsigned short* Be = Bt + (size_t)e * KD * ND;
    const int n0 = blockIdx.x * 128;

    __shared__ __align__(16) unsigned short As[128 * 32];
    __shared__ __align__(16) unsigned short Bs[128 * 32];

    f32x4 acc[4][4] = {};
    const int srow = lane >> 2, scol = (lane & 3) * 8;   // staging lane map
    const int r = lane & 15, hseg = (lane >> 4) * 8;     // fragment lane map

    for (int k0 = 0; k0 < KD; k0 += 32) {
        #pragma unroll
        for (int c = 0; c < 2; ++c) {
            const int ch = wv * 2 + c;                    // wave-uniform chunk id
            const int row = ch * 16 + srow;
            load_lds16(A  + (size_t)(row0 + row) * KD + k0 + scol, As + ch * 512);
            load_lds16(Be + (size_t)(n0  + row) * KD + k0 + scol, Bs + ch * 512);
        }
        __syncthreads();
        short8 af[4], bfr[4];
        #pragma unroll
        for (int m = 0; m < 4; ++m)
            af[m] = *reinterpret_cast<const short8*>(As + (wr*64 + m*16 + r) * 32 + hseg);
        #pragma unroll
        for (int nn = 0; nn < 4; ++nn)
            bfr[nn] = *reinterpret_cast<const short8*>(Bs + (wc*64 + nn*16 + r) * 32 + hseg);
        #pragma unroll
        for (int m = 0; m < 4; ++m)
            #pragma unroll
            for (int nn = 0; nn < 4; ++nn)
                acc[m][nn] = __builtin_amdgcn_mfma_f32_16x16x32_bf16(af[m], bfr[nn], acc[m][nn], 0, 0, 0);
        __syncthreads();
    }

    const int col = lane & 15, rb = (lane >> 4) * 4;      // C/D: col=lane&15, row=(lane>>4)*4+j
    #pragma unroll
    for (int m = 0; m < 4; ++m)
        #pragma unroll
        for (int nn = 0; nn < 4; ++nn)
            #pragma unroll
            for (int j = 0; j < 4; ++j) {
                const int grow = row0 + wr*64 + m*16 + rb + j;
                const int gcol = n0  + wc*64 + nn*16 + col;
                float v = acc[m][nn][j];
                if (GELU) {
                    v = 0.5f * v * (1.0f + erff(v * 0.70710678118654752f));
                    ((unsigned short*)Cout)[(size_t)grow * ND + gcol] = f2bf(v);
                } else {
                    ((float*)Cout)[(size_t)grow * ND + gcol] = v;
                }
            }
}

__global__ __launch_bounds__(256) void combine_kernel(
    const float* __restrict__ sout, const float* __restrict__ scores,
    const int* __restrict__ slot_of, float* __restrict__ out)
{
    const int n = blockIdx.x;
    const float s0 = scores[2*n], s1 = scores[2*n+1];
    const int sa = slot_of[2*n], sb = slot_of[2*n+1];
    const int d = threadIdx.x * 4;
    const float4 va = *reinterpret_cast<const float4*>(sout + (size_t)sa * DIM + d);
    const float4 vb = *reinterpret_cast<const float4*>(sout + (size_t)sb * DIM + d);
    float4 o;
    o.x = s0*va.x + s1*vb.x; o.y = s0*va.y + s1*vb.y;
    o.z = s0*va.z + s1*vb.z; o.w = s0*va.w + s1*vb.w;
    *reinterpret_cast<float4*>(out + (size_t)n * DIM + d) = o;
}

__global__ void aux_kernel(const float* __restrict__ aux, float* __restrict__ out) {
    if (threadIdx.x == 0) {
        const float t = 0.125f;
        out[(size_t)NTOK * DIM] = 0.01f * t * (logf(t) - aux[0] / (float)(NTOK * NE));
    }
}

// ---- workspace layout (bytes) ----
constexpr size_t OFF_AUX    = 1024 + 512;
constexpr size_t OFF_SCORES = 2048;
constexpr size_t OFF_IDX    = OFF_SCORES + (size_t)NTOK * 2 * 4;
constexpr size_t OFF_SLOT   = OFF_IDX    + (size_t)NTOK * 2 * 4;
constexpr size_t OFF_GWT    = 65536;                       // 32 KB fp32 gw^T
constexpr size_t OFF_XG     = 131072;
constexpr size_t OFF_W1T    = OFF_XG  + (size_t)MAXROWS * DIM  * 2;
constexpr size_t OFF_W2T    = OFF_W1T + (size_t)NE * DIM * HDIM * 2;
constexpr size_t OFF_H      = OFF_W2T + (size_t)NE * DIM * HDIM * 2;
constexpr size_t OFF_SOUT   = OFF_H   + (size_t)MAXROWS * HDIM * 2;
constexpr size_t WS_NEED    = OFF_SOUT + (size_t)MAXROWS * DIM  * 4;

extern "C" void kernel_launch(void* const* d_in, const int* in_sizes, int n_in,
                              void* d_out, int out_size, void* d_ws, size_t ws_size,
                              hipStream_t stream) {
    const float* x  = (const float*)d_in[0];
    const float* gw = (const float*)d_in[1];
    const float* gb = (const float*)d_in[2];
    const float* w1 = (const float*)d_in[3];
    const float* w2 = (const float*)d_in[4];
    float* out = (float*)d_out;

    if (ws_size < WS_NEED) return;   // fail loudly (output stays poisoned)

    char* ws = (char*)d_ws;
    int*   hdr     = (int*)ws;
    float* aux     = (float*)(ws + OFF_AUX);
    float* scores  = (float*)(ws + OFF_SCORES);
    int*   eidx    = (int*)(ws + OFF_IDX);
    int*   slot_of = (int*)(ws + OFF_SLOT);
    float* gwt     = (float*)(ws + OFF_GWT);
    unsigned short* xg  = (unsigned short*)(ws + OFF_XG);
    unsigned short* w1t = (unsigned short*)(ws + OFF_W1T);
    unsigned short* w2t = (unsigned short*)(ws + OFF_W2T);
    unsigned short* h   = (unsigned short*)(ws + OFF_H);
    float* sout         = (float*)(ws + OFF_SOUT);

    init_kernel<<<1, 256, 0, stream>>>(hdr);
    hipMemsetAsync(aux, 0, 4, stream);
    gwt_kernel<<<DIM*NE/256, 256, 0, stream>>>(gw, gwt);
    transpose_kernel<<<dim3(HDIM/32, DIM/32, NE), dim3(32, 8), 0, stream>>>(w1, w1t, DIM, HDIM);
    transpose_kernel<<<dim3(DIM/32, HDIM/32, NE), dim3(32, 8), 0, stream>>>(w2, w2t, HDIM, DIM);
    gate_kernel<<<NTOK/4, 256, 0, stream>>>(x, gwt, gb, scores, eidx, hdr, aux);
    offsets_kernel<<<1, 64, 0, stream>>>(hdr);
    assign_kernel<<<2*NTOK/256, 256, 0, stream>>>(eidx, hdr, slot_of);
    gather_kernel<<<2*NTOK/4, 256, 0, stream>>>(x, slot_of, xg);
    gemm_kernel<DIM, HDIM, true ><<<dim3(HDIM/128, MBLK), 256, 0, stream>>>(xg, w1t, (void*)h, hdr);
    gemm_kernel<HDIM, DIM, false><<<dim3(DIM/128, MBLK), 256, 0, stream>>>(h, w2t, (void*)sout, hdr);
    combine_kernel<<<NTOK, 256, 0, stream>>>(sout, scores, slot_of, out);
    aux_kernel<<<1, 64, 0, stream>>>(aux, out);
}

// Round 4
// 225.672 us; speedup vs baseline: 1.3785x; 1.3785x over previous
//
#include <hip/hip_runtime.h>
#include <cstdint>
#include <cstddef>

#define NTOK 4096           // B*S
#define DIM  1024           // D
#define HDIM 2048           // H
#define NE   8              // experts
#define BM   128            // GEMM row tile
#define MAXROWS (2*NTOK + NE*BM)   // 9216 worst-case padded slots
#define MBLK (MAXROWS/BM)          // 72 m-blocks (fixed grid)

typedef __attribute__((ext_vector_type(8))) short short8;
typedef __attribute__((ext_vector_type(4))) float f32x4;
typedef __attribute__((ext_vector_type(4))) unsigned short u16x4;

__device__ __forceinline__ unsigned short f2bf(float f) {
    union { float f; unsigned int u; } v; v.f = f;
    return (unsigned short)((v.u + 0x7FFFu + ((v.u >> 16) & 1u)) >> 16);
}

__device__ __forceinline__ void load_lds16(const void* g, void* l) {
    __builtin_amdgcn_global_load_lds(
        (const __attribute__((address_space(1))) void*)(uintptr_t)g,
        (__attribute__((address_space(3))) void*)(uintptr_t)l, 16, 0, 0);
}

// hdr layout (ints): [16..24] padded offsets (off[8]=padded_total), [32 + 16*e] cursors
__global__ void init_kernel(int* hdr) {
    hdr[threadIdx.x] = 0;   // 256 ints
}

// gw [1024][8] f32 -> gwt [8][1024] f32
__global__ __launch_bounds__(256) void gwt_kernel(const float* __restrict__ gw, float* __restrict__ gwt) {
    const int i = blockIdx.x * 256 + threadIdx.x;   // 8192 total
    const int d = i >> 3, e = i & 7;
    gwt[e * DIM + d] = gw[i];
}

// Atomic-free gate: writes scores, eidx, and per-token aux partial.
__global__ __launch_bounds__(256) void gate_kernel(
    const float* __restrict__ x, const float* __restrict__ gwt, const float* __restrict__ gb,
    float* __restrict__ scores, int* __restrict__ eidx, float* __restrict__ auxp)
{
    const int tid = threadIdx.x, lane = tid & 63, wv = tid >> 6;
    const int n = blockIdx.x * 4 + wv;
    float a[NE] = {0.f,0.f,0.f,0.f,0.f,0.f,0.f,0.f};
    const float* xr = x + (size_t)n * DIM;
    #pragma unroll
    for (int c = 0; c < 4; ++c) {
        const int d0 = c * 256 + lane * 4;
        const float4 xv = *reinterpret_cast<const float4*>(xr + d0);
        #pragma unroll
        for (int e = 0; e < NE; ++e) {
            const float4 gv = *reinterpret_cast<const float4*>(gwt + e * DIM + d0);  // coalesced
            a[e] = fmaf(xv.x, gv.x, a[e]);
            a[e] = fmaf(xv.y, gv.y, a[e]);
            a[e] = fmaf(xv.z, gv.z, a[e]);
            a[e] = fmaf(xv.w, gv.w, a[e]);
        }
    }
    #pragma unroll
    for (int e = 0; e < NE; ++e)
        #pragma unroll
        for (int off = 32; off > 0; off >>= 1)
            a[e] += __shfl_xor(a[e], off);
    if (lane == 0) {
        float lg[NE], slg = 0.f, mx = -1e30f;
        #pragma unroll
        for (int e = 0; e < NE; ++e) { lg[e] = a[e] + gb[e]; slg += lg[e]; mx = fmaxf(mx, lg[e]); }
        float se = 0.f;
        #pragma unroll
        for (int e = 0; e < NE; ++e) se += expf(lg[e] - mx);
        const float lz = mx + logf(se);
        int i0 = 0;
        #pragma unroll
        for (int e = 1; e < NE; ++e) if (lg[e] > lg[i0]) i0 = e;
        int i1 = (i0 == 0) ? 1 : 0;
        #pragma unroll
        for (int e = 0; e < NE; ++e) if (e != i0 && lg[e] > lg[i1]) i1 = e;
        const float ex = expf(lg[i1] - lg[i0]);
        const float p0 = 1.f / (1.f + ex);
        scores[2*n]   = p0;
        scores[2*n+1] = ex * p0;
        eidx[2*n]   = i0;
        eidx[2*n+1] = i1;
        auxp[n] = slg - 8.f * lz;           // sum_e logp_e for this token (no atomics)
    }
}

// Single block: histogram of 8192 expert indices + padded offsets. No global atomics.
__global__ __launch_bounds__(1024) void hist_offsets_kernel(const int* __restrict__ eidx, int* __restrict__ hdr)
{
    __shared__ int cnt[NE];
    const int tid = threadIdx.x, lane = tid & 63, wv = tid >> 6;
    if (tid < NE) cnt[tid] = 0;
    __syncthreads();
    int local[NE] = {0,0,0,0,0,0,0,0};
    #pragma unroll
    for (int j = 0; j < 8; ++j) {
        const int e = eidx[j * 1024 + tid];
        #pragma unroll
        for (int k = 0; k < NE; ++k) local[k] += (e == k);
    }
    #pragma unroll
    for (int k = 0; k < NE; ++k)
        #pragma unroll
        for (int off = 32; off > 0; off >>= 1)
            local[k] += __shfl_xor(local[k], off);
    if (lane == 0)
        #pragma unroll
        for (int k = 0; k < NE; ++k) atomicAdd(&cnt[k], local[k]);   // 16 waves x 8 LDS atomics
    __syncthreads();
    if (tid == 0) {
        int off = 0;
        for (int e = 0; e < NE; ++e) {
            hdr[16 + e] = off;
            off += (cnt[e] + BM - 1) & ~(BM - 1);
        }
        hdr[16 + NE] = off;   // padded_total
    }
}

// Block-aggregated slot assignment: 256 pairs/block, 8 returning atomics/block (spread lines).
__global__ __launch_bounds__(256) void assign_kernel(
    const int* __restrict__ eidx, int* __restrict__ hdr, int* __restrict__ slot_of)
{
    __shared__ int cnt[NE];
    __shared__ int base[NE];
    const int tid = threadIdx.x;
    const int p = blockIdx.x * 256 + tid;
    if (tid < NE) cnt[tid] = 0;
    __syncthreads();
    const int e = eidx[p];
    const int pos = atomicAdd(&cnt[e], 1);          // LDS atomic
    __syncthreads();
    if (tid < NE) base[tid] = atomicAdd(&hdr[32 + 16 * tid], cnt[tid]);  // own cacheline
    __syncthreads();
    slot_of[p] = hdr[16 + e] + base[e] + pos;
}

// Atomic-free gather/cast: one wave per pair.
__global__ __launch_bounds__(256) void gather_kernel(
    const float* __restrict__ x, const int* __restrict__ slot_of, unsigned short* __restrict__ xg)
{
    const int tid = threadIdx.x, lane = tid & 63, wv = tid >> 6;
    const int pair = blockIdx.x * 4 + wv;        // pair = n*2 + k
    const int n = pair >> 1;
    const int slot = slot_of[pair];
    const float* xr = x + (size_t)n * DIM;
    unsigned short* dst = xg + (size_t)slot * DIM;
    for (int d0 = lane * 4; d0 < DIM; d0 += 256) {
        const float4 xv = *reinterpret_cast<const float4*>(xr + d0);
        u16x4 o = { f2bf(xv.x), f2bf(xv.y), f2bf(xv.z), f2bf(xv.w) };
        *reinterpret_cast<u16x4*>(dst + d0) = o;
    }
}

// in: [E][R][C] f32  ->  out: [E][C][R] bf16
__global__ __launch_bounds__(256) void transpose_kernel(
    const float* __restrict__ in, unsigned short* __restrict__ out, int R, int C)
{
    __shared__ float tile[32][33];
    const int e = blockIdx.z;
    in  += (size_t)e * R * C;
    out += (size_t)e * R * C;
    const int c0 = blockIdx.x * 32, r0 = blockIdx.y * 32;
    const int tx = threadIdx.x, ty = threadIdx.y;
    #pragma unroll
    for (int j = 0; j < 4; ++j)
        tile[ty + 8*j][tx] = in[(size_t)(r0 + ty + 8*j) * C + c0 + tx];
    __syncthreads();
    #pragma unroll
    for (int j = 0; j < 4; ++j)
        out[(size_t)(c0 + ty + 8*j) * R + r0 + tx] = f2bf(tile[tx][ty + 8*j]);
}

// C[row][n] = (GELU? gelu : id)(A[row][:] @ B_e[:][n]);  A:[rows][KD] bf16, Bt:[E][ND][KD] bf16
template<int KD, int ND, bool GELU>
__global__ __launch_bounds__(256, 2) void gemm_kernel(
    const unsigned short* __restrict__ A, const unsigned short* __restrict__ Bt,
    void* __restrict__ Cout, const int* __restrict__ hdr)
{
    const int tid = threadIdx.x, lane = tid & 63, wv = tid >> 6;
    const int wr = wv >> 1, wc = wv & 1;
    const int row0 = blockIdx.y * BM;
    if (row0 >= hdr[16 + NE]) return;          // beyond padded_total
    int e = 0;
    while (e < NE - 1 && hdr[16 + e + 1] <= row0) ++e;
    const unsigned short* Be = Bt + (size_t)e * KD * ND;
    const int n0 = blockIdx.x * 128;

    __shared__ __align__(16) unsigned short As[128 * 32];
    __shared__ __align__(16) unsigned short Bs[128 * 32];

    f32x4 acc[4][4] = {};
    const int srow = lane >> 2, scol = (lane & 3) * 8;   // staging lane map
    const int r = lane & 15, hseg = (lane >> 4) * 8;     // fragment lane map

    for (int k0 = 0; k0 < KD; k0 += 32) {
        #pragma unroll
        for (int c = 0; c < 2; ++c) {
            const int ch = wv * 2 + c;                    // wave-uniform chunk id
            const int row = ch * 16 + srow;
            load_lds16(A  + (size_t)(row0 + row) * KD + k0 + scol, As + ch * 512);
            load_lds16(Be + (size_t)(n0  + row) * KD + k0 + scol, Bs + ch * 512);
        }
        __syncthreads();
        short8 af[4], bfr[4];
        #pragma unroll
        for (int m = 0; m < 4; ++m)
            af[m] = *reinterpret_cast<const short8*>(As + (wr*64 + m*16 + r) * 32 + hseg);
        #pragma unroll
        for (int nn = 0; nn < 4; ++nn)
            bfr[nn] = *reinterpret_cast<const short8*>(Bs + (wc*64 + nn*16 + r) * 32 + hseg);
        #pragma unroll
        for (int m = 0; m < 4; ++m)
            #pragma unroll
            for (int nn = 0; nn < 4; ++nn)
                acc[m][nn] = __builtin_amdgcn_mfma_f32_16x16x32_bf16(af[m], bfr[nn], acc[m][nn], 0, 0, 0);
        __syncthreads();
    }

    const int col = lane & 15, rb = (lane >> 4) * 4;      // C/D: col=lane&15, row=(lane>>4)*4+j
    #pragma unroll
    for (int m = 0; m < 4; ++m)
        #pragma unroll
        for (int nn = 0; nn < 4; ++nn)
            #pragma unroll
            for (int j = 0; j < 4; ++j) {
                const int grow = row0 + wr*64 + m*16 + rb + j;
                const int gcol = n0  + wc*64 + nn*16 + col;
                float v = acc[m][nn][j];
                if (GELU) {
                    v = 0.5f * v * (1.0f + erff(v * 0.70710678118654752f));
                    ((unsigned short*)Cout)[(size_t)grow * ND + gcol] = f2bf(v);
                } else {
                    ((float*)Cout)[(size_t)grow * ND + gcol] = v;
                }
            }
}

__global__ __launch_bounds__(256) void combine_kernel(
    const float* __restrict__ sout, const float* __restrict__ scores,
    const int* __restrict__ slot_of, float* __restrict__ out)
{
    const int n = blockIdx.x;
    const float s0 = scores[2*n], s1 = scores[2*n+1];
    const int sa = slot_of[2*n], sb = slot_of[2*n+1];
    const int d = threadIdx.x * 4;
    const float4 va = *reinterpret_cast<const float4*>(sout + (size_t)sa * DIM + d);
    const float4 vb = *reinterpret_cast<const float4*>(sout + (size_t)sb * DIM + d);
    float4 o;
    o.x = s0*va.x + s1*vb.x; o.y = s0*va.y + s1*vb.y;
    o.z = s0*va.z + s1*vb.z; o.w = s0*va.w + s1*vb.w;
    *reinterpret_cast<float4*>(out + (size_t)n * DIM + d) = o;
}

// Reduce the 4096 per-token aux partials; write aux loss scalar.
__global__ __launch_bounds__(256) void aux_kernel(const float* __restrict__ auxp, float* __restrict__ out)
{
    __shared__ float red[4];
    const int tid = threadIdx.x, lane = tid & 63, wv = tid >> 6;
    float s = 0.f;
    for (int i = tid; i < NTOK; i += 256) s += auxp[i];
    #pragma unroll
    for (int off = 32; off > 0; off >>= 1) s += __shfl_xor(s, off);
    if (lane == 0) red[wv] = s;
    __syncthreads();
    if (tid == 0) {
        const float tot = red[0] + red[1] + red[2] + red[3];
        const float t = 0.125f;
        out[(size_t)NTOK * DIM] = 0.01f * t * (logf(t) - tot / (float)(NTOK * NE));
    }
}

// ---- workspace layout (bytes) ----
constexpr size_t OFF_SCORES = 2048;
constexpr size_t OFF_IDX    = OFF_SCORES + (size_t)NTOK * 2 * 4;
constexpr size_t OFF_SLOT   = OFF_IDX    + (size_t)NTOK * 2 * 4;
constexpr size_t OFF_AUXP   = OFF_SLOT   + (size_t)NTOK * 2 * 4;   // 16 KB
constexpr size_t OFF_GWT    = OFF_AUXP   + (size_t)NTOK * 4;       // 32 KB fp32 gw^T
constexpr size_t OFF_XG     = 131072;
constexpr size_t OFF_W1T    = OFF_XG  + (size_t)MAXROWS * DIM  * 2;
constexpr size_t OFF_W2T    = OFF_W1T + (size_t)NE * DIM * HDIM * 2;
constexpr size_t OFF_H      = OFF_W2T + (size_t)NE * DIM * HDIM * 2;
constexpr size_t OFF_SOUT   = OFF_H   + (size_t)MAXROWS * HDIM * 2;
constexpr size_t WS_NEED    = OFF_SOUT + (size_t)MAXROWS * DIM  * 4;

extern "C" void kernel_launch(void* const* d_in, const int* in_sizes, int n_in,
                              void* d_out, int out_size, void* d_ws, size_t ws_size,
                              hipStream_t stream) {
    const float* x  = (const float*)d_in[0];
    const float* gw = (const float*)d_in[1];
    const float* gb = (const float*)d_in[2];
    const float* w1 = (const float*)d_in[3];
    const float* w2 = (const float*)d_in[4];
    float* out = (float*)d_out;

    if (ws_size < WS_NEED) return;   // fail loudly (output stays poisoned)

    char* ws = (char*)d_ws;
    int*   hdr     = (int*)ws;
    float* scores  = (float*)(ws + OFF_SCORES);
    int*   eidx    = (int*)(ws + OFF_IDX);
    int*   slot_of = (int*)(ws + OFF_SLOT);
    float* auxp    = (float*)(ws + OFF_AUXP);
    float* gwt     = (float*)(ws + OFF_GWT);
    unsigned short* xg  = (unsigned short*)(ws + OFF_XG);
    unsigned short* w1t = (unsigned short*)(ws + OFF_W1T);
    unsigned short* w2t = (unsigned short*)(ws + OFF_W2T);
    unsigned short* h   = (unsigned short*)(ws + OFF_H);
    float* sout         = (float*)(ws + OFF_SOUT);

    init_kernel<<<1, 256, 0, stream>>>(hdr);
    gwt_kernel<<<DIM*NE/256, 256, 0, stream>>>(gw, gwt);
    transpose_kernel<<<dim3(HDIM/32, DIM/32, NE), dim3(32, 8), 0, stream>>>(w1, w1t, DIM, HDIM);
    transpose_kernel<<<dim3(DIM/32, HDIM/32, NE), dim3(32, 8), 0, stream>>>(w2, w2t, HDIM, DIM);
    gate_kernel<<<NTOK/4, 256, 0, stream>>>(x, gwt, gb, scores, eidx, auxp);
    hist_offsets_kernel<<<1, 1024, 0, stream>>>(eidx, hdr);
    assign_kernel<<<2*NTOK/256, 256, 0, stream>>>(eidx, hdr, slot_of);
    gather_kernel<<<2*NTOK/4, 256, 0, stream>>>(x, slot_of, xg);
    gemm_kernel<DIM, HDIM, true ><<<dim3(HDIM/128, MBLK), 256, 0, stream>>>(xg, w1t, (void*)h, hdr);
    gemm_kernel<HDIM, DIM, false><<<dim3(DIM/128, MBLK), 256, 0, stream>>>(h, w2t, (void*)sout, hdr);
    combine_kernel<<<NTOK, 256, 0, stream>>>(sout, scores, slot_of, out);
    aux_kernel<<<1, 256, 0, stream>>>(auxp, out);
}

// Round 5
// 208.969 us; speedup vs baseline: 1.4886x; 1.0799x over previous
//
#include <hip/hip_runtime.h>
#include <cstdint>
#include <cstddef>

#define NTOK 4096           // B*S
#define DIM  1024           // D
#define HDIM 2048           // H
#define NE   8              // experts
#define BM   128            // GEMM row tile
#define MAXROWS (2*NTOK + NE*BM)   // 9216 worst-case padded slots
#define MBLK (MAXROWS/BM)          // 72 m-blocks (fixed grid)

typedef __attribute__((ext_vector_type(8))) short short8;
typedef __attribute__((ext_vector_type(4))) float f32x4;
typedef __attribute__((ext_vector_type(4))) unsigned short u16x4;

__device__ __forceinline__ unsigned short f2bf(float f) {
    union { float f; unsigned int u; } v; v.f = f;
    return (unsigned short)((v.u + 0x7FFFu + ((v.u >> 16) & 1u)) >> 16);
}
__device__ __forceinline__ float bf2f(unsigned short u) {
    union { unsigned int u; float f; } v; v.u = ((unsigned int)u) << 16;
    return v.f;
}

__device__ __forceinline__ void load_lds16(const void* g, void* l) {
    __builtin_amdgcn_global_load_lds(
        (const __attribute__((address_space(1))) void*)(uintptr_t)g,
        (__attribute__((address_space(3))) void*)(uintptr_t)l, 16, 0, 0);
}

// hdr layout (ints): [16..24] padded offsets (off[8]=padded_total), [32 + 16*e] cursors
__global__ void init_kernel(int* hdr) {
    hdr[threadIdx.x] = 0;   // 256 ints
}

// gw [1024][8] f32 -> gwt [8][1024] f32
__global__ __launch_bounds__(256) void gwt_kernel(const float* __restrict__ gw, float* __restrict__ gwt) {
    const int i = blockIdx.x * 256 + threadIdx.x;   // 8192 total
    const int d = i >> 3, e = i & 7;
    gwt[e * DIM + d] = gw[i];
}

// Atomic-free gate: writes scores, eidx, and per-token aux partial.
__global__ __launch_bounds__(256) void gate_kernel(
    const float* __restrict__ x, const float* __restrict__ gwt, const float* __restrict__ gb,
    float* __restrict__ scores, int* __restrict__ eidx, float* __restrict__ auxp)
{
    const int tid = threadIdx.x, lane = tid & 63, wv = tid >> 6;
    const int n = blockIdx.x * 4 + wv;
    float a[NE] = {0.f,0.f,0.f,0.f,0.f,0.f,0.f,0.f};
    const float* xr = x + (size_t)n * DIM;
    #pragma unroll
    for (int c = 0; c < 4; ++c) {
        const int d0 = c * 256 + lane * 4;
        const float4 xv = *reinterpret_cast<const float4*>(xr + d0);
        #pragma unroll
        for (int e = 0; e < NE; ++e) {
            const float4 gv = *reinterpret_cast<const float4*>(gwt + e * DIM + d0);  // coalesced
            a[e] = fmaf(xv.x, gv.x, a[e]);
            a[e] = fmaf(xv.y, gv.y, a[e]);
            a[e] = fmaf(xv.z, gv.z, a[e]);
            a[e] = fmaf(xv.w, gv.w, a[e]);
        }
    }
    #pragma unroll
    for (int e = 0; e < NE; ++e)
        #pragma unroll
        for (int off = 32; off > 0; off >>= 1)
            a[e] += __shfl_xor(a[e], off);
    if (lane == 0) {
        float lg[NE], slg = 0.f, mx = -1e30f;
        #pragma unroll
        for (int e = 0; e < NE; ++e) { lg[e] = a[e] + gb[e]; slg += lg[e]; mx = fmaxf(mx, lg[e]); }
        float se = 0.f;
        #pragma unroll
        for (int e = 0; e < NE; ++e) se += expf(lg[e] - mx);
        const float lz = mx + logf(se);
        int i0 = 0;
        #pragma unroll
        for (int e = 1; e < NE; ++e) if (lg[e] > lg[i0]) i0 = e;
        int i1 = (i0 == 0) ? 1 : 0;
        #pragma unroll
        for (int e = 0; e < NE; ++e) if (e != i0 && lg[e] > lg[i1]) i1 = e;
        const float ex = expf(lg[i1] - lg[i0]);
        const float p0 = 1.f / (1.f + ex);
        scores[2*n]   = p0;
        scores[2*n+1] = ex * p0;
        eidx[2*n]   = i0;
        eidx[2*n+1] = i1;
        auxp[n] = slg - 8.f * lz;           // sum_e logp_e for this token (no atomics)
    }
}

// Single block: histogram of 8192 expert indices + padded offsets. No global atomics.
__global__ __launch_bounds__(1024) void hist_offsets_kernel(const int* __restrict__ eidx, int* __restrict__ hdr)
{
    __shared__ int cnt[NE];
    const int tid = threadIdx.x, lane = tid & 63;
    if (tid < NE) cnt[tid] = 0;
    __syncthreads();
    int local[NE] = {0,0,0,0,0,0,0,0};
    #pragma unroll
    for (int j = 0; j < 8; ++j) {
        const int e = eidx[j * 1024 + tid];
        #pragma unroll
        for (int k = 0; k < NE; ++k) local[k] += (e == k);
    }
    #pragma unroll
    for (int k = 0; k < NE; ++k)
        #pragma unroll
        for (int off = 32; off > 0; off >>= 1)
            local[k] += __shfl_xor(local[k], off);
    if (lane == 0)
        #pragma unroll
        for (int k = 0; k < NE; ++k) atomicAdd(&cnt[k], local[k]);   // 16 waves x 8 LDS atomics
    __syncthreads();
    if (tid == 0) {
        int off = 0;
        for (int e = 0; e < NE; ++e) {
            hdr[16 + e] = off;
            off += (cnt[e] + BM - 1) & ~(BM - 1);
        }
        hdr[16 + NE] = off;   // padded_total
    }
}

// Block-aggregated slot assignment: 256 pairs/block, 8 returning atomics/block (spread lines).
__global__ __launch_bounds__(256) void assign_kernel(
    const int* __restrict__ eidx, int* __restrict__ hdr, int* __restrict__ slot_of)
{
    __shared__ int cnt[NE];
    __shared__ int base[NE];
    const int tid = threadIdx.x;
    const int p = blockIdx.x * 256 + tid;
    if (tid < NE) cnt[tid] = 0;
    __syncthreads();
    const int e = eidx[p];
    const int pos = atomicAdd(&cnt[e], 1);          // LDS atomic
    __syncthreads();
    if (tid < NE) base[tid] = atomicAdd(&hdr[32 + 16 * tid], cnt[tid]);  // own cacheline
    __syncthreads();
    slot_of[p] = hdr[16 + e] + base[e] + pos;
}

// Atomic-free gather/cast: one wave per pair.
__global__ __launch_bounds__(256) void gather_kernel(
    const float* __restrict__ x, const int* __restrict__ slot_of, unsigned short* __restrict__ xg)
{
    const int tid = threadIdx.x, lane = tid & 63, wv = tid >> 6;
    const int pair = blockIdx.x * 4 + wv;        // pair = n*2 + k
    const int n = pair >> 1;
    const int slot = slot_of[pair];
    const float* xr = x + (size_t)n * DIM;
    unsigned short* dst = xg + (size_t)slot * DIM;
    for (int d0 = lane * 4; d0 < DIM; d0 += 256) {
        const float4 xv = *reinterpret_cast<const float4*>(xr + d0);
        u16x4 o = { f2bf(xv.x), f2bf(xv.y), f2bf(xv.z), f2bf(xv.w) };
        *reinterpret_cast<u16x4*>(dst + d0) = o;
    }
}

// in: [E][R][C] f32  ->  out: [E][C][R] bf16
__global__ __launch_bounds__(256) void transpose_kernel(
    const float* __restrict__ in, unsigned short* __restrict__ out, int R, int C)
{
    __shared__ float tile[32][33];
    const int e = blockIdx.z;
    in  += (size_t)e * R * C;
    out += (size_t)e * R * C;
    const int c0 = blockIdx.x * 32, r0 = blockIdx.y * 32;
    const int tx = threadIdx.x, ty = threadIdx.y;
    #pragma unroll
    for (int j = 0; j < 4; ++j)
        tile[ty + 8*j][tx] = in[(size_t)(r0 + ty + 8*j) * C + c0 + tx];
    __syncthreads();
    #pragma unroll
    for (int j = 0; j < 4; ++j)
        out[(size_t)(c0 + ty + 8*j) * R + r0 + tx] = f2bf(tile[tx][ty + 8*j]);
}

// C[row][n] = (GELU? gelu : id)(A[row][:] @ B_e[:][n]);  A:[rows][KD] bf16, Bt:[E][ND][KD] bf16
// Output is bf16 either way. Double-buffered LDS, counted vmcnt, raw barriers (T3-minimum).
template<int KD, int ND, bool GELU>
__global__ __launch_bounds__(256, 4) void gemm_kernel(
    const unsigned short* __restrict__ A, const unsigned short* __restrict__ Bt,
    unsigned short* __restrict__ Cout, const int* __restrict__ hdr)
{
    const int tid = threadIdx.x, lane = tid & 63, wv = tid >> 6;
    const int wr = wv >> 1, wc = wv & 1;
    const int row0 = blockIdx.y * BM;
    if (row0 >= hdr[16 + NE]) return;          // beyond padded_total (uniform)
    int e = 0;
    while (e < NE - 1 && hdr[16 + e + 1] <= row0) ++e;
    const unsigned short* Ae = A + (size_t)row0 * KD;
    const unsigned short* Be = Bt + (size_t)e * KD * ND + (size_t)(blockIdx.x * 128) * KD;

    __shared__ __align__(16) unsigned short As[2][128 * 32];
    __shared__ __align__(16) unsigned short Bs[2][128 * 32];

    f32x4 acc[4][4] = {};
    const int srow = lane >> 2, scol = (lane & 3) * 8;   // staging lane map (16B/lane)
    const int r = lane & 15, hseg = (lane >> 4) * 8;     // fragment lane map
    const int ch0 = wv * 2, ch1 = ch0 + 1;               // wave-uniform chunk ids

    auto STAGE = [&](int b, int k0) {
        load_lds16(Ae + (size_t)(ch0*16 + srow) * KD + k0 + scol, &As[b][ch0 * 512]);
        load_lds16(Ae + (size_t)(ch1*16 + srow) * KD + k0 + scol, &As[b][ch1 * 512]);
        load_lds16(Be + (size_t)(ch0*16 + srow) * KD + k0 + scol, &Bs[b][ch0 * 512]);
        load_lds16(Be + (size_t)(ch1*16 + srow) * KD + k0 + scol, &Bs[b][ch1 * 512]);
    };

    STAGE(0, 0);
    int cur = 0;
    for (int k0 = 0; k0 < KD; k0 += 32) {
        const int nk = k0 + 32;
        if (nk < KD) {
            STAGE(cur ^ 1, nk);                               // prefetch next tile
            asm volatile("s_waitcnt vmcnt(4)" ::: "memory");  // wait current tile only
        } else {
            asm volatile("s_waitcnt vmcnt(0)" ::: "memory");
        }
        __builtin_amdgcn_s_barrier();          // all waves' current-tile loads landed
        __builtin_amdgcn_sched_barrier(0);
        short8 af[4], bfr[4];
        #pragma unroll
        for (int m = 0; m < 4; ++m)
            af[m] = *reinterpret_cast<const short8*>(&As[cur][(wr*64 + m*16 + r) * 32 + hseg]);
        #pragma unroll
        for (int nn = 0; nn < 4; ++nn)
            bfr[nn] = *reinterpret_cast<const short8*>(&Bs[cur][(wc*64 + nn*16 + r) * 32 + hseg]);
        __builtin_amdgcn_s_setprio(1);
        #pragma unroll
        for (int m = 0; m < 4; ++m)
            #pragma unroll
            for (int nn = 0; nn < 4; ++nn)
                acc[m][nn] = __builtin_amdgcn_mfma_f32_16x16x32_bf16(af[m], bfr[nn], acc[m][nn], 0, 0, 0);
        __builtin_amdgcn_s_setprio(0);
        __builtin_amdgcn_s_barrier();          // reads of buf[cur] done -> next STAGE may overwrite
        __builtin_amdgcn_sched_barrier(0);
        cur ^= 1;
    }

    const int col = lane & 15, rb = (lane >> 4) * 4;      // C/D: col=lane&15, row=(lane>>4)*4+j
    #pragma unroll
    for (int m = 0; m < 4; ++m)
        #pragma unroll
        for (int nn = 0; nn < 4; ++nn)
            #pragma unroll
            for (int j = 0; j < 4; ++j) {
                const int grow = row0 + wr*64 + m*16 + rb + j;
                const int gcol = blockIdx.x * 128 + wc*64 + nn*16 + col;
                float v = acc[m][nn][j];
                if (GELU) v = 0.5f * v * (1.0f + erff(v * 0.70710678118654752f));
                Cout[(size_t)grow * ND + gcol] = f2bf(v);
            }
}

__global__ __launch_bounds__(256) void combine_kernel(
    const unsigned short* __restrict__ sout, const float* __restrict__ scores,
    const int* __restrict__ slot_of, float* __restrict__ out)
{
    const int n = blockIdx.x;
    const float s0 = scores[2*n], s1 = scores[2*n+1];
    const int sa = slot_of[2*n], sb = slot_of[2*n+1];
    const int d = threadIdx.x * 4;
    const u16x4 va = *reinterpret_cast<const u16x4*>(sout + (size_t)sa * DIM + d);
    const u16x4 vb = *reinterpret_cast<const u16x4*>(sout + (size_t)sb * DIM + d);
    float4 o;
    o.x = s0*bf2f(va.x) + s1*bf2f(vb.x);
    o.y = s0*bf2f(va.y) + s1*bf2f(vb.y);
    o.z = s0*bf2f(va.z) + s1*bf2f(vb.z);
    o.w = s0*bf2f(va.w) + s1*bf2f(vb.w);
    *reinterpret_cast<float4*>(out + (size_t)n * DIM + d) = o;
}

// Reduce the 4096 per-token aux partials; write aux loss scalar.
__global__ __launch_bounds__(256) void aux_kernel(const float* __restrict__ auxp, float* __restrict__ out)
{
    __shared__ float red[4];
    const int tid = threadIdx.x, lane = tid & 63, wv = tid >> 6;
    float s = 0.f;
    for (int i = tid; i < NTOK; i += 256) s += auxp[i];
    #pragma unroll
    for (int off = 32; off > 0; off >>= 1) s += __shfl_xor(s, off);
    if (lane == 0) red[wv] = s;
    __syncthreads();
    if (tid == 0) {
        const float tot = red[0] + red[1] + red[2] + red[3];
        const float t = 0.125f;
        out[(size_t)NTOK * DIM] = 0.01f * t * (logf(t) - tot / (float)(NTOK * NE));
    }
}

// ---- workspace layout (bytes) ----
constexpr size_t OFF_SCORES = 2048;
constexpr size_t OFF_IDX    = OFF_SCORES + (size_t)NTOK * 2 * 4;
constexpr size_t OFF_SLOT   = OFF_IDX    + (size_t)NTOK * 2 * 4;
constexpr size_t OFF_AUXP   = OFF_SLOT   + (size_t)NTOK * 2 * 4;   // 16 KB
constexpr size_t OFF_GWT    = OFF_AUXP   + (size_t)NTOK * 4;       // 32 KB fp32 gw^T
constexpr size_t OFF_XG     = 131072;
constexpr size_t OFF_W1T    = OFF_XG  + (size_t)MAXROWS * DIM  * 2;
constexpr size_t OFF_W2T    = OFF_W1T + (size_t)NE * DIM * HDIM * 2;
constexpr size_t OFF_H      = OFF_W2T + (size_t)NE * DIM * HDIM * 2;
constexpr size_t OFF_SOUT   = OFF_H   + (size_t)MAXROWS * HDIM * 2;
constexpr size_t WS_NEED    = OFF_SOUT + (size_t)MAXROWS * DIM  * 4;

extern "C" void kernel_launch(void* const* d_in, const int* in_sizes, int n_in,
                              void* d_out, int out_size, void* d_ws, size_t ws_size,
                              hipStream_t stream) {
    const float* x  = (const float*)d_in[0];
    const float* gw = (const float*)d_in[1];
    const float* gb = (const float*)d_in[2];
    const float* w1 = (const float*)d_in[3];
    const float* w2 = (const float*)d_in[4];
    float* out = (float*)d_out;

    if (ws_size < WS_NEED) return;   // fail loudly (output stays poisoned)

    char* ws = (char*)d_ws;
    int*   hdr     = (int*)ws;
    float* scores  = (float*)(ws + OFF_SCORES);
    int*   eidx    = (int*)(ws + OFF_IDX);
    int*   slot_of = (int*)(ws + OFF_SLOT);
    float* auxp    = (float*)(ws + OFF_AUXP);
    float* gwt     = (float*)(ws + OFF_GWT);
    unsigned short* xg  = (unsigned short*)(ws + OFF_XG);
    unsigned short* w1t = (unsigned short*)(ws + OFF_W1T);
    unsigned short* w2t = (unsigned short*)(ws + OFF_W2T);
    unsigned short* h   = (unsigned short*)(ws + OFF_H);
    unsigned short* sout= (unsigned short*)(ws + OFF_SOUT);

    init_kernel<<<1, 256, 0, stream>>>(hdr);
    gwt_kernel<<<DIM*NE/256, 256, 0, stream>>>(gw, gwt);
    transpose_kernel<<<dim3(HDIM/32, DIM/32, NE), dim3(32, 8), 0, stream>>>(w1, w1t, DIM, HDIM);
    transpose_kernel<<<dim3(DIM/32, HDIM/32, NE), dim3(32, 8), 0, stream>>>(w2, w2t, HDIM, DIM);
    gate_kernel<<<NTOK/4, 256, 0, stream>>>(x, gwt, gb, scores, eidx, auxp);
    hist_offsets_kernel<<<1, 1024, 0, stream>>>(eidx, hdr);
    assign_kernel<<<2*NTOK/256, 256, 0, stream>>>(eidx, hdr, slot_of);
    gather_kernel<<<2*NTOK/4, 256, 0, stream>>>(x, slot_of, xg);
    gemm_kernel<DIM, HDIM, true ><<<dim3(HDIM/128, MBLK), 256, 0, stream>>>(xg, w1t, h, hdr);
    gemm_kernel<HDIM, DIM, false><<<dim3(DIM/128, MBLK), 256, 0, stream>>>(h, w2t, sout, hdr);
    combine_kernel<<<NTOK, 256, 0, stream>>>(sout, scores, slot_of, out);
    aux_kernel<<<1, 256, 0, stream>>>(auxp, out);
}

// Round 6
// 203.920 us; speedup vs baseline: 1.5255x; 1.0248x over previous
//
#include <hip/hip_runtime.h>
#include <cstdint>
#include <cstddef>

#define NTOK 4096           // B*S
#define DIM  1024           // D
#define HDIM 2048           // H
#define NE   8              // experts
#define BM   128            // GEMM row tile
#define MAXROWS (2*NTOK + NE*BM)   // 9216 worst-case padded slots
#define MBLK (MAXROWS/BM)          // 72 m-blocks (fixed grid)

typedef __attribute__((ext_vector_type(8))) short short8;
typedef __attribute__((ext_vector_type(4))) float f32x4;
typedef __attribute__((ext_vector_type(4))) unsigned short u16x4;
typedef __attribute__((ext_vector_type(8))) unsigned short u16x8;

__device__ __forceinline__ unsigned short f2bf(float f) {
    union { float f; unsigned int u; } v; v.f = f;
    return (unsigned short)((v.u + 0x7FFFu + ((v.u >> 16) & 1u)) >> 16);
}
__device__ __forceinline__ float bf2f(unsigned short u) {
    union { unsigned int u; float f; } v; v.u = ((unsigned int)u) << 16;
    return v.f;
}

__device__ __forceinline__ void load_lds16(const void* g, void* l) {
    __builtin_amdgcn_global_load_lds(
        (const __attribute__((address_space(1))) void*)(uintptr_t)g,
        (__attribute__((address_space(3))) void*)(uintptr_t)l, 16, 0, 0);
}

// hdr layout (ints): [16..24] padded offsets (off[8]=padded_total), [32 + 16*e] cursors
__global__ void init_kernel(int* hdr) {
    hdr[threadIdx.x] = 0;   // 256 ints
}

// gw [1024][8] f32 -> gwt [8][1024] f32
__global__ __launch_bounds__(256) void gwt_kernel(const float* __restrict__ gw, float* __restrict__ gwt) {
    const int i = blockIdx.x * 256 + threadIdx.x;   // 8192 total
    const int d = i >> 3, e = i & 7;
    gwt[e * DIM + d] = gw[i];
}

// Atomic-free gate: writes scores, eidx, per-token aux partial, and token-major bf16 x.
__global__ __launch_bounds__(256) void gate_kernel(
    const float* __restrict__ x, const float* __restrict__ gwt, const float* __restrict__ gb,
    float* __restrict__ scores, int* __restrict__ eidx, float* __restrict__ auxp,
    unsigned short* __restrict__ xbf)
{
    const int tid = threadIdx.x, lane = tid & 63, wv = tid >> 6;
    const int n = blockIdx.x * 4 + wv;
    float a[NE] = {0.f,0.f,0.f,0.f,0.f,0.f,0.f,0.f};
    const float* xr = x + (size_t)n * DIM;
    unsigned short* xo = xbf + (size_t)n * DIM;
    #pragma unroll
    for (int c = 0; c < 4; ++c) {
        const int d0 = c * 256 + lane * 4;
        const float4 xv = *reinterpret_cast<const float4*>(xr + d0);
        u16x4 o = { f2bf(xv.x), f2bf(xv.y), f2bf(xv.z), f2bf(xv.w) };
        *reinterpret_cast<u16x4*>(xo + d0) = o;
        #pragma unroll
        for (int e = 0; e < NE; ++e) {
            const float4 gv = *reinterpret_cast<const float4*>(gwt + e * DIM + d0);  // coalesced
            a[e] = fmaf(xv.x, gv.x, a[e]);
            a[e] = fmaf(xv.y, gv.y, a[e]);
            a[e] = fmaf(xv.z, gv.z, a[e]);
            a[e] = fmaf(xv.w, gv.w, a[e]);
        }
    }
    #pragma unroll
    for (int e = 0; e < NE; ++e)
        #pragma unroll
        for (int off = 32; off > 0; off >>= 1)
            a[e] += __shfl_xor(a[e], off);
    if (lane == 0) {
        float lg[NE], slg = 0.f, mx = -1e30f;
        #pragma unroll
        for (int e = 0; e < NE; ++e) { lg[e] = a[e] + gb[e]; slg += lg[e]; mx = fmaxf(mx, lg[e]); }
        float se = 0.f;
        #pragma unroll
        for (int e = 0; e < NE; ++e) se += expf(lg[e] - mx);
        const float lz = mx + logf(se);
        int i0 = 0;
        #pragma unroll
        for (int e = 1; e < NE; ++e) if (lg[e] > lg[i0]) i0 = e;
        int i1 = (i0 == 0) ? 1 : 0;
        #pragma unroll
        for (int e = 0; e < NE; ++e) if (e != i0 && lg[e] > lg[i1]) i1 = e;
        const float ex = expf(lg[i1] - lg[i0]);
        const float p0 = 1.f / (1.f + ex);
        scores[2*n]   = p0;
        scores[2*n+1] = ex * p0;
        eidx[2*n]   = i0;
        eidx[2*n+1] = i1;
        auxp[n] = slg - 8.f * lz;           // sum_e logp_e for this token (no atomics)
    }
}

// Single block: histogram of 8192 expert indices + padded offsets. No global atomics.
__global__ __launch_bounds__(1024) void hist_offsets_kernel(const int* __restrict__ eidx, int* __restrict__ hdr)
{
    __shared__ int cnt[NE];
    const int tid = threadIdx.x, lane = tid & 63;
    if (tid < NE) cnt[tid] = 0;
    __syncthreads();
    int local[NE] = {0,0,0,0,0,0,0,0};
    #pragma unroll
    for (int j = 0; j < 8; ++j) {
        const int e = eidx[j * 1024 + tid];
        #pragma unroll
        for (int k = 0; k < NE; ++k) local[k] += (e == k);
    }
    #pragma unroll
    for (int k = 0; k < NE; ++k)
        #pragma unroll
        for (int off = 32; off > 0; off >>= 1)
            local[k] += __shfl_xor(local[k], off);
    if (lane == 0)
        #pragma unroll
        for (int k = 0; k < NE; ++k) atomicAdd(&cnt[k], local[k]);   // LDS atomics
    __syncthreads();
    if (tid == 0) {
        int off = 0;
        for (int e = 0; e < NE; ++e) {
            hdr[16 + e] = off;
            off += (cnt[e] + BM - 1) & ~(BM - 1);
        }
        hdr[16 + NE] = off;   // padded_total
    }
}

// Block-aggregated slot assignment + slot->token inverse map.
__global__ __launch_bounds__(256) void assign_kernel(
    const int* __restrict__ eidx, int* __restrict__ hdr, int* __restrict__ slot_of,
    int* __restrict__ s2t)
{
    __shared__ int cnt[NE];
    __shared__ int base[NE];
    const int tid = threadIdx.x;
    const int p = blockIdx.x * 256 + tid;
    if (tid < NE) cnt[tid] = 0;
    __syncthreads();
    const int e = eidx[p];
    const int pos = atomicAdd(&cnt[e], 1);          // LDS atomic
    __syncthreads();
    if (tid < NE) base[tid] = atomicAdd(&hdr[32 + 16 * tid], cnt[tid]);  // own cacheline
    __syncthreads();
    const int slot = hdr[16 + e] + base[e] + pos;
    slot_of[p] = slot;
    s2t[slot] = p >> 1;                             // token of this slot
}

// in: [E][R][C] f32  ->  out: [E][C][R] bf16, 64x64 tiles, coalesced u16x8 stores.
__global__ __launch_bounds__(256) void transpose_kernel(
    const float* __restrict__ in, unsigned short* __restrict__ out, int R, int C)
{
    __shared__ unsigned short tile[64][72];   // [c][r], pad 8 shorts: rows 144 B
    const int e = blockIdx.z;
    in  += (size_t)e * R * C;
    out += (size_t)e * R * C;
    const int c0 = blockIdx.x * 64, r0 = blockIdx.y * 64;
    const int t = threadIdx.x;
    const int lc = (t & 15) * 4, lr = t >> 4;
    #pragma unroll
    for (int p = 0; p < 4; ++p) {
        const int r = lr + p * 16;
        const float4 v = *reinterpret_cast<const float4*>(in + (size_t)(r0 + r) * C + c0 + lc);
        tile[lc+0][r] = f2bf(v.x);
        tile[lc+1][r] = f2bf(v.y);
        tile[lc+2][r] = f2bf(v.z);
        tile[lc+3][r] = f2bf(v.w);
    }
    __syncthreads();
    const int oc = t >> 2, os = (t & 3) * 16;
    const u16x8 a = *reinterpret_cast<const u16x8*>(&tile[oc][os]);
    const u16x8 b = *reinterpret_cast<const u16x8*>(&tile[oc][os + 8]);
    unsigned short* orow = out + (size_t)(c0 + oc) * R + r0 + os;
    *reinterpret_cast<u16x8*>(orow)     = a;
    *reinterpret_cast<u16x8*>(orow + 8) = b;
}

// C[row][n] = (GELU? gelu : id)(A[row][:] @ B_e[:][n]);  A:[*][KD] bf16, Bt:[E][ND][KD] bf16
// 3-deep LDS pipeline, counted vmcnt(8), XOR bank swizzle, optional slot->token gather on A.
template<int KD, int ND, bool GELU, bool GATHER>
__global__ __launch_bounds__(256, 2) void gemm_kernel(
    const unsigned short* __restrict__ A, const unsigned short* __restrict__ Bt,
    unsigned short* __restrict__ Cout, const int* __restrict__ hdr, const int* __restrict__ s2t)
{
    const int tid = threadIdx.x, lane = tid & 63, wv = tid >> 6;
    const int wr = wv >> 1, wc = wv & 1;
    const int row0 = blockIdx.y * BM;
    if (row0 >= hdr[16 + NE]) return;          // beyond padded_total (uniform)
    int e = 0;
    while (e < NE - 1 && hdr[16 + e + 1] <= row0) ++e;
    const unsigned short* Be = Bt + (size_t)e * KD * ND + (size_t)(blockIdx.x * 128) * KD;

    // 3 buffers x (A 4096 shorts | B 4096 shorts) = 48 KB
    __shared__ __align__(16) unsigned short lds[3 * 8192];

    f32x4 acc[4][4] = {};
    const int srow = lane >> 2;
    const int scolX = (((lane & 3) ^ ((lane >> 3) & 3)) * 8);   // swizzled source col (elements)
    const int ch0 = wv * 2, ch1 = ch0 + 1;                      // wave-uniform chunk ids

    // per-thread global A rows (resolved once; GATHER indirects slot->token)
    const int ra0 = row0 + ch0 * 16 + srow, ra1 = row0 + ch1 * 16 + srow;
    const size_t ga0 = (size_t)(GATHER ? s2t[ra0] : ra0) * KD;
    const size_t ga1 = (size_t)(GATHER ? s2t[ra1] : ra1) * KD;
    const size_t gb0 = (size_t)(ch0 * 16 + srow) * KD;
    const size_t gb1 = (size_t)(ch1 * 16 + srow) * KD;

    auto STAGE = [&](unsigned off, int k0) {   // off in shorts
        load_lds16(A  + ga0 + k0 + scolX, &lds[off + ch0 * 512]);
        load_lds16(A  + ga1 + k0 + scolX, &lds[off + ch1 * 512]);
        load_lds16(Be + gb0 + k0 + scolX, &lds[off + 4096 + ch0 * 512]);
        load_lds16(Be + gb1 + k0 + scolX, &lds[off + 4096 + ch1 * 512]);
    };

    const int r = lane & 15;
    const int hsegX = (((lane >> 4) ^ ((r >> 1) & 3)) * 8);     // swizzled frag col (shorts)

    unsigned o0 = 0, o1 = 8192, o2 = 16384;
    STAGE(o0, 0);
    STAGE(o1, 32);
    const int NT = KD / 32;
    for (int t = 0; t < NT; ++t) {
        if (t + 2 < NT) {
            STAGE(o2, (t + 2) * 32);                              // prefetch 2 ahead
            asm volatile("s_waitcnt vmcnt(8)" ::: "memory");      // tile t landed
        } else if (t + 1 < NT) {
            asm volatile("s_waitcnt vmcnt(4)" ::: "memory");
        } else {
            asm volatile("s_waitcnt vmcnt(0)" ::: "memory");
        }
        __builtin_amdgcn_s_barrier();          // all waves' tile-t loads landed
        __builtin_amdgcn_sched_barrier(0);
        short8 af[4], bfr[4];
        #pragma unroll
        for (int m = 0; m < 4; ++m)
            af[m] = *reinterpret_cast<const short8*>(&lds[o0 + (wr*64 + m*16 + r) * 32 + hsegX]);
        #pragma unroll
        for (int nn = 0; nn < 4; ++nn)
            bfr[nn] = *reinterpret_cast<const short8*>(&lds[o0 + 4096 + (wc*64 + nn*16 + r) * 32 + hsegX]);
        __builtin_amdgcn_s_setprio(1);
        #pragma unroll
        for (int m = 0; m < 4; ++m)
            #pragma unroll
            for (int nn = 0; nn < 4; ++nn)
                acc[m][nn] = __builtin_amdgcn_mfma_f32_16x16x32_bf16(af[m], bfr[nn], acc[m][nn], 0, 0, 0);
        __builtin_amdgcn_s_setprio(0);
        __builtin_amdgcn_sched_barrier(0);
        __builtin_amdgcn_s_barrier();          // reads of o0 done -> t+1's STAGE may overwrite
        const unsigned tmp = o0; o0 = o1; o1 = o2; o2 = tmp;
    }

    const int col = lane & 15, rb = (lane >> 4) * 4;      // C/D: col=lane&15, row=(lane>>4)*4+j
    #pragma unroll
    for (int m = 0; m < 4; ++m)
        #pragma unroll
        for (int nn = 0; nn < 4; ++nn)
            #pragma unroll
            for (int j = 0; j < 4; ++j) {
                const int grow = row0 + wr*64 + m*16 + rb + j;
                const int gcol = blockIdx.x * 128 + wc*64 + nn*16 + col;
                float v = acc[m][nn][j];
                if (GELU) v = 0.5f * v * (1.0f + erff(v * 0.70710678118654752f));
                Cout[(size_t)grow * ND + gcol] = f2bf(v);
            }
}

__global__ __launch_bounds__(256) void combine_kernel(
    const unsigned short* __restrict__ sout, const float* __restrict__ scores,
    const int* __restrict__ slot_of, float* __restrict__ out)
{
    const int n = blockIdx.x;
    const float s0 = scores[2*n], s1 = scores[2*n+1];
    const int sa = slot_of[2*n], sb = slot_of[2*n+1];
    const int d = threadIdx.x * 4;
    const u16x4 va = *reinterpret_cast<const u16x4*>(sout + (size_t)sa * DIM + d);
    const u16x4 vb = *reinterpret_cast<const u16x4*>(sout + (size_t)sb * DIM + d);
    float4 o;
    o.x = s0*bf2f(va.x) + s1*bf2f(vb.x);
    o.y = s0*bf2f(va.y) + s1*bf2f(vb.y);
    o.z = s0*bf2f(va.z) + s1*bf2f(vb.z);
    o.w = s0*bf2f(va.w) + s1*bf2f(vb.w);
    *reinterpret_cast<float4*>(out + (size_t)n * DIM + d) = o;
}

// Reduce the 4096 per-token aux partials; write aux loss scalar.
__global__ __launch_bounds__(256) void aux_kernel(const float* __restrict__ auxp, float* __restrict__ out)
{
    __shared__ float red[4];
    const int tid = threadIdx.x, lane = tid & 63, wv = tid >> 6;
    float s = 0.f;
    for (int i = tid; i < NTOK; i += 256) s += auxp[i];
    #pragma unroll
    for (int off = 32; off > 0; off >>= 1) s += __shfl_xor(s, off);
    if (lane == 0) red[wv] = s;
    __syncthreads();
    if (tid == 0) {
        const float tot = red[0] + red[1] + red[2] + red[3];
        const float t = 0.125f;
        out[(size_t)NTOK * DIM] = 0.01f * t * (logf(t) - tot / (float)(NTOK * NE));
    }
}

// ---- workspace layout (bytes) ----
constexpr size_t OFF_SCORES = 2048;
constexpr size_t OFF_IDX    = OFF_SCORES + (size_t)NTOK * 2 * 4;
constexpr size_t OFF_SLOT   = OFF_IDX    + (size_t)NTOK * 2 * 4;
constexpr size_t OFF_AUXP   = OFF_SLOT   + (size_t)NTOK * 2 * 4;
constexpr size_t OFF_S2T    = OFF_AUXP   + (size_t)NTOK * 4;
constexpr size_t OFF_GWT    = OFF_S2T    + (size_t)MAXROWS * 4;
constexpr size_t OFF_XBF    = 262144;
constexpr size_t OFF_W1T    = OFF_XBF + (size_t)NTOK * DIM * 2;
constexpr size_t OFF_W2T    = OFF_W1T + (size_t)NE * DIM * HDIM * 2;
constexpr size_t OFF_H      = OFF_W2T + (size_t)NE * DIM * HDIM * 2;
constexpr size_t OFF_SOUT   = OFF_H   + (size_t)MAXROWS * HDIM * 2;
constexpr size_t WS_NEED    = OFF_SOUT + (size_t)MAXROWS * DIM * 2;

extern "C" void kernel_launch(void* const* d_in, const int* in_sizes, int n_in,
                              void* d_out, int out_size, void* d_ws, size_t ws_size,
                              hipStream_t stream) {
    const float* x  = (const float*)d_in[0];
    const float* gw = (const float*)d_in[1];
    const float* gb = (const float*)d_in[2];
    const float* w1 = (const float*)d_in[3];
    const float* w2 = (const float*)d_in[4];
    float* out = (float*)d_out;

    if (ws_size < WS_NEED) return;   // fail loudly (output stays poisoned)

    char* ws = (char*)d_ws;
    int*   hdr     = (int*)ws;
    float* scores  = (float*)(ws + OFF_SCORES);
    int*   eidx    = (int*)(ws + OFF_IDX);
    int*   slot_of = (int*)(ws + OFF_SLOT);
    float* auxp    = (float*)(ws + OFF_AUXP);
    int*   s2t     = (int*)(ws + OFF_S2T);
    float* gwt     = (float*)(ws + OFF_GWT);
    unsigned short* xbf = (unsigned short*)(ws + OFF_XBF);
    unsigned short* w1t = (unsigned short*)(ws + OFF_W1T);
    unsigned short* w2t = (unsigned short*)(ws + OFF_W2T);
    unsigned short* h   = (unsigned short*)(ws + OFF_H);
    unsigned short* sout= (unsigned short*)(ws + OFF_SOUT);

    init_kernel<<<1, 256, 0, stream>>>(hdr);
    hipMemsetAsync(s2t, 0, (size_t)MAXROWS * 4, stream);   // pad slots -> token 0 (finite)
    gwt_kernel<<<DIM*NE/256, 256, 0, stream>>>(gw, gwt);
    transpose_kernel<<<dim3(HDIM/64, DIM/64, NE), 256, 0, stream>>>(w1, w1t, DIM, HDIM);
    transpose_kernel<<<dim3(DIM/64, HDIM/64, NE), 256, 0, stream>>>(w2, w2t, HDIM, DIM);
    gate_kernel<<<NTOK/4, 256, 0, stream>>>(x, gwt, gb, scores, eidx, auxp, xbf);
    hist_offsets_kernel<<<1, 1024, 0, stream>>>(eidx, hdr);
    assign_kernel<<<2*NTOK/256, 256, 0, stream>>>(eidx, hdr, slot_of, s2t);
    gemm_kernel<DIM, HDIM, true,  true ><<<dim3(HDIM/128, MBLK), 256, 0, stream>>>(xbf, w1t, h, hdr, s2t);
    gemm_kernel<HDIM, DIM, false, false><<<dim3(DIM/128, MBLK), 256, 0, stream>>>(h, w2t, sout, hdr, s2t);
    combine_kernel<<<NTOK, 256, 0, stream>>>(sout, scores, slot_of, out);
    aux_kernel<<<1, 256, 0, stream>>>(auxp, out);
}